// Round 11
// baseline (83.283 us; speedup 1.0000x reference)
//
#include <hip/hip_runtime.h>

#define LOG2E 1.4426950408889634f

typedef short bf16x8 __attribute__((ext_vector_type(8)));
typedef short short4v __attribute__((ext_vector_type(4)));
typedef float f32x4 __attribute__((ext_vector_type(4)));
typedef _Float16 half4v __attribute__((ext_vector_type(4)));
typedef unsigned u32x4 __attribute__((ext_vector_type(4)));
typedef unsigned __attribute__((address_space(1))) u32g;
typedef unsigned __attribute__((address_space(3))) u32l;

#define MFMA16(a, b, c) __builtin_amdgcn_mfma_f32_16x16x32_bf16((a), (b), (c), 0, 0, 0)

__device__ __forceinline__ short f2bf(float f) {
  unsigned u = __builtin_bit_cast(unsigned, f);
  u += 0x7FFFu + ((u >> 16) & 1u);
  return (short)(u >> 16);
}

__device__ __forceinline__ unsigned cvtpk(float lo, float hi) {
  unsigned r;
  asm("v_cvt_pk_bf16_f32 %0, %1, %2" : "=v"(r) : "v"(lo), "v"(hi));
  return r;
}

__device__ __forceinline__ void g2l16(void* lds, const void* g) {
  __builtin_amdgcn_global_load_lds((u32g*)const_cast<void*>(g), (u32l*)lds, 16, 0, 0);
}

// ---------------------------------------------------------------------------
// GroupNorm: x (B,512,1024) f32 -> xn_t (B,1024,512) bf16   [transposed for GEMM]
// ---------------------------------------------------------------------------
__global__ __launch_bounds__(256) void gn_kernel(const float* __restrict__ x,
                                                 const float* __restrict__ gamma,
                                                 const float* __restrict__ beta,
                                                 short* __restrict__ xn_t) {
  __shared__ _Float16 xs[16 * 1024];  // 32 KB, row = channel, swizzled
  __shared__ float red[8];
  const int bg = blockIdx.x;
  const int b = bg >> 5, g = bg & 31;
  const int t = threadIdx.x;
  const float4* gx4 = (const float4*)(x + (size_t)(b * 512 + g * 16) * 1024);
  float s1 = 0.f, s2 = 0.f;
  for (int i = 0; i < 16; ++i) {
    float4 v = gx4[t + 256 * i];
    s1 += (v.x + v.y) + (v.z + v.w);
    s2 += (v.x * v.x + v.y * v.y) + (v.z * v.z + v.w * v.w);
    half4v pk = {(_Float16)v.x, (_Float16)v.y, (_Float16)v.z, (_Float16)v.w};
    *(half4v*)((char*)xs + i * 2048 + ((8 * t) ^ ((i & 7) << 4))) = pk;
  }
  for (int m = 1; m < 64; m <<= 1) {
    s1 += __shfl_xor(s1, m);
    s2 += __shfl_xor(s2, m);
  }
  if ((t & 63) == 0) {
    red[(t >> 6) * 2] = s1;
    red[(t >> 6) * 2 + 1] = s2;
  }
  __syncthreads();
  s1 = (red[0] + red[2]) + (red[4] + red[6]);
  s2 = (red[1] + red[3]) + (red[5] + red[7]);
  const float mean = s1 * (1.f / 16384.f);
  const float var = s2 * (1.f / 16384.f) - mean * mean;
  const float rstd = rsqrtf(var + 1e-6f);
  const int ci = t & 15;
  const float ga = gamma[g * 16 + ci] * rstd;
  const float be = beta[g * 16 + ci] - mean * ga;
  short* dst = xn_t + (size_t)b * 1024 * 512 + g * 16 + ci;
  const int sw = (ci & 7) << 4;
  for (int i = 0; i < 64; ++i) {
    int n = (t >> 4) + 16 * i;
    float v = (float)*(const _Float16*)((const char*)xs + ci * 2048 + ((2 * n) ^ sw));
    dst[(size_t)n * 512] = f2bf(fmaf(v, ga, be));
  }
}

// ---------------------------------------------------------------------------
__global__ __launch_bounds__(256) void f2bf_kernel(const float* __restrict__ src,
                                                   short* __restrict__ dst, int n4) {
  int i = blockIdx.x * 256 + threadIdx.x;
  if (i < n4) {
    float4 v = ((const float4*)src)[i];
    short4v o = {f2bf(v.x), f2bf(v.y), f2bf(v.z), f2bf(v.w)};
    *(short4v*)(dst + (size_t)i * 4) = o;
  }
}

// ---------------------------------------------------------------------------
// QKV GEMM, 2-phase prefetch + chunk-XOR LDS swizzle + XCD-LOCALITY SWIZZLE:
// 1-D grid 768; xcd = id&7, slot s = id>>3 (0..95). Panel-group pg (one
// (nbase,b) xn-panel, 128 KB) = xcd*8 + s/12; the 12 mbase-blocks of a panel
// sit consecutively on ONE XCD -> panel read once into that L2. Per-XCD set:
// W 1.5 MB + 8 panels = 2.5 MB < 4 MB L2. Kills the ~200 MB L3 re-fetch.
// ---------------------------------------------------------------------------
__global__ __launch_bounds__(256) void qkv_gemm(const short* __restrict__ W,
                                                const short* __restrict__ xn,
                                                const float* __restrict__ bias,
                                                short* __restrict__ qbuf,
                                                short* __restrict__ kbuf,
                                                short* __restrict__ vtbuf) {
  __shared__ short a_sm[2][128 * 32];
  __shared__ short b_sm[2][128 * 32];
  const int t = threadIdx.x;
  const int lane = t & 63, w = t >> 6;
  const int id = blockIdx.x;
  const int s = id >> 3;
  const int pg = (id & 7) * 8 + s / 12;  // 0..63 = (b, nIdx)
  const int mbase = (s % 12) * 128;
  const int nbase = (pg & 7) * 128;
  const int b = pg >> 3;
  const short* Asrc = W + (size_t)mbase * 512;
  const short* Bsrc = xn + (size_t)b * 1024 * 512 + (size_t)nbase * 512;

  const int j0 = t, j1 = t + 256;
  const int r0 = j0 >> 2, c0 = ((j0 & 3) ^ ((j0 >> 3) & 3)) * 8;
  const int r1 = j1 >> 2, c1 = ((j1 & 3) ^ ((j1 >> 3) & 3)) * 8;

#define STAGE(bi, kt)                                                 \
  {                                                                   \
    const int k0s = (kt) * 32;                                        \
    g2l16(&a_sm[bi][j0 * 8], Asrc + (size_t)r0 * 512 + k0s + c0);     \
    g2l16(&a_sm[bi][j1 * 8], Asrc + (size_t)r1 * 512 + k0s + c1);     \
    g2l16(&b_sm[bi][j0 * 8], Bsrc + (size_t)r0 * 512 + k0s + c0);     \
    g2l16(&b_sm[bi][j1 * 8], Bsrc + (size_t)r1 * 512 + k0s + c1);     \
  }

  const int wm = (w >> 1) * 64, wn = (w & 1) * 64;
  const int col = lane & 15, rg = lane >> 4;

  f32x4 acc[4][4] = {};

  STAGE(0, 0)
  __syncthreads();
  int cur = 0;

  for (int kt = 0; kt < 16; ++kt) {
    if (kt < 15) STAGE(cur ^ 1, kt + 1);
    bf16x8 af[4], bfr[4];
#pragma unroll
    for (int mf = 0; mf < 4; ++mf) {
      const int row = wm + mf * 16 + col;
      af[mf] = *(const bf16x8*)&a_sm[cur][row * 32 + ((rg ^ ((row >> 1) & 3)) * 8)];
    }
#pragma unroll
    for (int nf = 0; nf < 4; ++nf) {
      const int row = wn + nf * 16 + col;
      bfr[nf] = *(const bf16x8*)&b_sm[cur][row * 32 + ((rg ^ ((row >> 1) & 3)) * 8)];
    }
    __builtin_amdgcn_s_setprio(1);
#pragma unroll
    for (int mf = 0; mf < 4; ++mf)
#pragma unroll
      for (int nf = 0; nf < 4; ++nf)
        acc[mf][nf] = MFMA16(af[mf], bfr[nf], acc[mf][nf]);
    __builtin_amdgcn_s_setprio(0);
    __syncthreads();
    cur ^= 1;
  }
#undef STAGE

  const int section = mbase >> 9;
  for (int mf = 0; mf < 4; ++mf) {
    const int o0 = mbase + wm + mf * 16 + rg * 4;
    const int h = (o0 >> 6) & 7, d0 = o0 & 63;
    float b4[4];
    for (int r = 0; r < 4; ++r) b4[r] = bias[o0 + r];
    for (int nf = 0; nf < 4; ++nf) {
      const int n = nbase + wn + nf * 16 + col;
      if (section < 2) {
        short4v pkv;
        for (int r = 0; r < 4; ++r) pkv[r] = f2bf(acc[mf][nf][r] + b4[r]);
        short* dst = (section == 0) ? qbuf : kbuf;
        *(short4v*)&dst[((size_t)(b * 8 + h) * 1024 + n) * 64 + d0] = pkv;
      } else {
        for (int r = 0; r < 4; ++r)
          vtbuf[((size_t)(b * 8 + h) * 64 + d0 + r) * 1024 + n] =
              f2bf(acc[mf][nf][r] + b4[r]);
      }
    }
  }
}

// ---------------------------------------------------------------------------
// Flash attention, swapped-operand, 32 q-rows/wave, INTRA-BLOCK KV-SPLIT
// (unchanged from R10 — grid is already XCD-local: id%8 = bh%8).
// ---------------------------------------------------------------------------
__global__ __launch_bounds__(512, 4) void attn_kernel(const short* __restrict__ qbuf,
                                                      const short* __restrict__ kbuf,
                                                      const short* __restrict__ vtbuf,
                                                      short* __restrict__ ao) {
  __shared__ char smem[65536];
  const int t = threadIdx.x, lane = t & 63, w = t >> 6;
  const int col = lane & 15, rg = lane >> 4;
  const int grp = w >> 2, wq = w & 3;
  const int tg = t & 255;  // thread id within group (group = 4 waves)
  const int bh = blockIdx.x, qt = blockIdx.y;
  const int b = bh >> 3, h = bh & 7;
  const int qbase = qt * 128 + wq * 32;

  short* kb_ = (short*)(smem + grp * 32768);          // [2][64*64] K bufs
  short* vb_ = (short*)(smem + grp * 32768 + 16384);  // [2][64*64] V bufs

  // Q fragments (B-operand): aq[mf][kc], lane col = q, k = kc*32 + rg*8 + e
  bf16x8 aq[2][2];
  {
    const short* qp = qbuf + ((size_t)bh * 1024 + qbase) * 64;
#pragma unroll
    for (int mf = 0; mf < 2; ++mf)
#pragma unroll
      for (int kc = 0; kc < 2; ++kc)
        aq[mf][kc] = *(const bf16x8*)&qp[(mf * 16 + col) * 64 + kc * 32 + rg * 8];
  }

  // group kv-offsets: K rows += grp*512 ; V^T cols += grp*512
  const short* kp0 = kbuf + (size_t)bh * 65536 + grp * 32768;
  const short* vp0 = vtbuf + (size_t)bh * 65536 + grp * 512;

  uint4 kr[2], vr[2];
#define LOADK(kt)                                                                  \
  _Pragma("unroll") for (int i = 0; i < 2; ++i) {                                  \
    int j = tg + 256 * i;                                                          \
    kr[i] = *(const uint4*)&kp0[((size_t)(kt)*64 + (j >> 3)) * 64 + (j & 7) * 8];  \
  }
#define LOADV(kt)                                                                  \
  _Pragma("unroll") for (int i = 0; i < 2; ++i) {                                  \
    int j = tg + 256 * i;                                                          \
    vr[i] = *(const uint4*)&vp0[(size_t)(j >> 3) * 1024 + (kt)*64 + (j & 7) * 8];  \
  }
#define WRITEK(bi)                                                                 \
  _Pragma("unroll") for (int i = 0; i < 2; ++i) {                                  \
    int j = tg + 256 * i;                                                          \
    int row = j >> 3, off = j & 7;                                                 \
    *(uint4*)((char*)kb_ + (bi)*8192 + row * 128 + ((off * 16) ^ ((row & 7) << 4))) = kr[i]; \
  }
#define WRITEV(bi)                                                                 \
  _Pragma("unroll") for (int i = 0; i < 2; ++i) {                                  \
    int j = tg + 256 * i;                                                          \
    int d = j >> 3, g = j & 7;                                                     \
    int base = (g >> 2) * 64 + (g & 1) * 32 + ((g >> 1) & 1) * 8;                  \
    char* vb = (char*)vb_ + (bi)*8192 + d * 128;                                   \
    uint2 lo = {vr[i].x, vr[i].y}, hi = {vr[i].z, vr[i].w};                        \
    *(uint2*)(vb + ((base) ^ ((d & 7) << 4))) = lo;                                \
    *(uint2*)(vb + ((base + 16) ^ ((d & 7) << 4))) = hi;                           \
  }

  f32x4 oacc[2][4] = {};
  float mrun[2] = {-3e38f, -3e38f}, lrun[2] = {0.f, 0.f};
  const float kSL2E = 0.125f * LOG2E;  // attn scale folded into log2 domain
  int cur = 0;

  // prologue: tile 0 staged; writes consume loads with a counted vmcnt wait
  LOADK(0) LOADV(0) WRITEK(0) WRITEV(0)
  __syncthreads();

  for (int kt = 0; kt < 8; ++kt) {
    // issue next-tile loads FIRST (right after the barrier) — they stay in
    // flight across the whole compute span; consumed by WRITE before barrier
    if (kt < 7) { LOADK(kt + 1) LOADV(kt + 1) }

    // S^T = K * Q^T : K fragment read once, shared by both mf
    f32x4 sT[2][4];
    __builtin_amdgcn_s_setprio(1);
#pragma unroll
    for (int nf = 0; nf < 4; ++nf) {
      const int n = nf * 16 + col;
      const char* kb = (const char*)kb_ + cur * 8192 + n * 128;
      const int sw = (n & 7) << 4;
      bf16x8 bk0 = *(const bf16x8*)(kb + ((rg * 16) ^ sw));
      bf16x8 bk1 = *(const bf16x8*)(kb + ((64 + rg * 16) ^ sw));
#pragma unroll
      for (int mf = 0; mf < 2; ++mf) {
        f32x4 z = {};
        z = MFMA16(bk0, aq[mf][0], z);
        sT[mf][nf] = MFMA16(bk1, aq[mf][1], z);
      }
    }
    __builtin_amdgcn_s_setprio(0);

    unsigned pk[2][4][2];
#pragma unroll
    for (int mf = 0; mf < 2; ++mf) {
      f32x4 mv = sT[mf][0];
#pragma unroll
      for (int nf = 1; nf < 4; ++nf)
#pragma unroll
        for (int r = 0; r < 4; ++r) mv[r] = fmaxf(mv[r], sT[mf][nf][r]);
      float mx = fmaxf(fmaxf(mv[0], mv[1]), fmaxf(mv[2], mv[3]));
      mx = fmaxf(mx, __shfl_xor(mx, 16));
      mx = fmaxf(mx, __shfl_xor(mx, 32));
      const float pmax = mx * 0.125f;
      if (!__all(pmax <= mrun[mf] + 8.f)) {  // defer-max (THR=8)
        const float mnew = fmaxf(mrun[mf], pmax);
        const float alpha = __builtin_amdgcn_exp2f((mrun[mf] - mnew) * LOG2E);
        mrun[mf] = mnew;
        lrun[mf] *= alpha;
#pragma unroll
        for (int df = 0; df < 4; ++df) oacc[mf][df] *= alpha;
      }
      const float nege = mrun[mf] * LOG2E;
      float psum = 0.f;
#pragma unroll
      for (int nf = 0; nf < 4; ++nf) {
        float p0 = __builtin_amdgcn_exp2f(fmaf(sT[mf][nf][0], kSL2E, -nege));
        float p1 = __builtin_amdgcn_exp2f(fmaf(sT[mf][nf][1], kSL2E, -nege));
        float p2 = __builtin_amdgcn_exp2f(fmaf(sT[mf][nf][2], kSL2E, -nege));
        float p3 = __builtin_amdgcn_exp2f(fmaf(sT[mf][nf][3], kSL2E, -nege));
        psum += (p0 + p1) + (p2 + p3);
        pk[mf][nf][0] = cvtpk(p0, p1);
        pk[mf][nf][1] = cvtpk(p2, p3);
      }
      psum += __shfl_xor(psum, 16);
      psum += __shfl_xor(psum, 32);
      lrun[mf] += psum;
    }

    // O^T += V^T * P^T : shared V b128 read feeds both Q-fragments' MFMAs
    __builtin_amdgcn_s_setprio(1);
#pragma unroll
    for (int kc = 0; kc < 2; ++kc) {
      bf16x8 pb[2];
#pragma unroll
      for (int mf = 0; mf < 2; ++mf) {
        u32x4 pbu = {pk[mf][2 * kc][0], pk[mf][2 * kc][1], pk[mf][2 * kc + 1][0],
                     pk[mf][2 * kc + 1][1]};
        pb[mf] = __builtin_bit_cast(bf16x8, pbu);
      }
#pragma unroll
      for (int df = 0; df < 4; ++df) {
        const int d = df * 16 + col;
        bf16x8 av = *(const bf16x8*)((const char*)vb_ + cur * 8192 + d * 128 +
                                     ((kc * 64 + rg * 16) ^ ((d & 7) << 4)));
#pragma unroll
        for (int mf = 0; mf < 2; ++mf) oacc[mf][df] = MFMA16(av, pb[mf], oacc[mf][df]);
      }
    }
    __builtin_amdgcn_s_setprio(0);

    if (kt < 7) { WRITEK(cur ^ 1) WRITEV(cur ^ 1) }  // counted vmcnt wait here
    __syncthreads();                                  // drains nothing extra
    cur ^= 1;
  }

  // ---- in-block kv-split combine (LDS overlay on K/V buffers) ----
  f32x4* o_lds = (f32x4*)smem;                 // 32 KB: [w4][mf][df][lane]
  float* ml_lds = (float*)(smem + 32768);      // 4 KB: [w4][mf][lane][2]
  if (grp == 1) {
#pragma unroll
    for (int mf = 0; mf < 2; ++mf) {
#pragma unroll
      for (int df = 0; df < 4; ++df)
        o_lds[(((wq * 2 + mf) * 4) + df) * 64 + lane] = oacc[mf][df];
      ml_lds[((wq * 2 + mf) * 64 + lane) * 2] = mrun[mf];
      ml_lds[((wq * 2 + mf) * 64 + lane) * 2 + 1] = lrun[mf];
    }
  }
  __syncthreads();
  if (grp == 0) {
#pragma unroll
    for (int mf = 0; mf < 2; ++mf) {
      const float m1 = ml_lds[((wq * 2 + mf) * 64 + lane) * 2];
      const float l1 = ml_lds[((wq * 2 + mf) * 64 + lane) * 2 + 1];
      const float m = fmaxf(mrun[mf], m1);
      const float a0 = __builtin_amdgcn_exp2f((mrun[mf] - m) * LOG2E);
      const float a1 = __builtin_amdgcn_exp2f((m1 - m) * LOG2E);
      const float rl = 1.f / (lrun[mf] * a0 + l1 * a1);
      const int q = qbase + mf * 16 + col;
      short* dst = ao + ((size_t)b * 1024 + q) * 512 + h * 64;
#pragma unroll
      for (int df = 0; df < 4; ++df) {
        f32x4 o1 = o_lds[(((wq * 2 + mf) * 4) + df) * 64 + lane];
        short4v pkv;
#pragma unroll
        for (int r = 0; r < 4; ++r)
          pkv[r] = f2bf((oacc[mf][df][r] * a0 + o1[r] * a1) * rl);
        *(short4v*)&dst[df * 16 + rg * 4] = pkv;
      }
    }
  }
#undef LOADK
#undef LOADV
#undef WRITEK
#undef WRITEV
}

// ---------------------------------------------------------------------------
// Proj GEMM + bias + fp32 residual, 2-phase prefetch + swizzle, BM=64 tile,
// XCD-locality swizzle (8 m-blocks of one (nbase,b) panel per XCD slot run).
// ---------------------------------------------------------------------------
__global__ __launch_bounds__(256) void proj_gemm(const short* __restrict__ W,
                                                 const short* __restrict__ ao,
                                                 const float* __restrict__ bias,
                                                 const float* __restrict__ x,
                                                 float* __restrict__ out) {
  __shared__ short a_sm[2][64 * 32];
  __shared__ short b_sm[2][128 * 32];
  const int t = threadIdx.x;
  const int lane = t & 63, w = t >> 6;
  const int id = blockIdx.x;
  const int s = id >> 3;
  const int pg = (id & 7) * 8 + s / 8;  // 0..63 = (b, nIdx)
  const int mbase = (s % 8) * 64;
  const int nbase = (pg & 7) * 128;
  const int b = pg >> 3;
  const short* Asrc = W + (size_t)mbase * 512;
  const short* Bsrc = ao + (size_t)b * 1024 * 512 + (size_t)nbase * 512;

  const int j0 = t, j1 = t + 256;
  const int r0 = j0 >> 2, c0 = ((j0 & 3) ^ ((j0 >> 3) & 3)) * 8;
  const int r1 = j1 >> 2, c1 = ((j1 & 3) ^ ((j1 >> 3) & 3)) * 8;

#define STAGE(bi, kt)                                                 \
  {                                                                   \
    const int k0s = (kt) * 32;                                        \
    g2l16(&a_sm[bi][j0 * 8], Asrc + (size_t)r0 * 512 + k0s + c0);     \
    g2l16(&b_sm[bi][j0 * 8], Bsrc + (size_t)r0 * 512 + k0s + c0);     \
    g2l16(&b_sm[bi][j1 * 8], Bsrc + (size_t)r1 * 512 + k0s + c1);     \
  }

  const int wm = (w >> 1) * 32, wn = (w & 1) * 64;
  const int col = lane & 15, rg = lane >> 4;

  f32x4 acc[2][4] = {};

  STAGE(0, 0)
  __syncthreads();
  int cur = 0;

  for (int kt = 0; kt < 16; ++kt) {
    if (kt < 15) STAGE(cur ^ 1, kt + 1);
    bf16x8 af[2], bfr[4];
#pragma unroll
    for (int mf = 0; mf < 2; ++mf) {
      const int row = wm + mf * 16 + col;
      af[mf] = *(const bf16x8*)&a_sm[cur][row * 32 + ((rg ^ ((row >> 1) & 3)) * 8)];
    }
#pragma unroll
    for (int nf = 0; nf < 4; ++nf) {
      const int row = wn + nf * 16 + col;
      bfr[nf] = *(const bf16x8*)&b_sm[cur][row * 32 + ((rg ^ ((row >> 1) & 3)) * 8)];
    }
    __builtin_amdgcn_s_setprio(1);
#pragma unroll
    for (int mf = 0; mf < 2; ++mf)
#pragma unroll
      for (int nf = 0; nf < 4; ++nf)
        acc[mf][nf] = MFMA16(af[mf], bfr[nf], acc[mf][nf]);
    __builtin_amdgcn_s_setprio(0);
    __syncthreads();
    cur ^= 1;
  }
#undef STAGE

  for (int mf = 0; mf < 2; ++mf) {
    const int o0 = mbase + wm + mf * 16 + rg * 4;
    float b4[4];
    for (int r = 0; r < 4; ++r) b4[r] = bias[o0 + r];
    for (int nf = 0; nf < 4; ++nf) {
      const int n = nbase + wn + nf * 16 + col;
      for (int r = 0; r < 4; ++r) {
        size_t idx = ((size_t)b * 512 + o0 + r) * 1024 + n;
        out[idx] = x[idx] + acc[mf][nf][r] + b4[r];
      }
    }
  }
}

// ---------------------------------------------------------------------------
extern "C" void kernel_launch(void* const* d_in, const int* in_sizes, int n_in,
                              void* d_out, int out_size, void* d_ws, size_t ws_size,
                              hipStream_t stream) {
  const float* x = (const float*)d_in[0];
  const float* gamma = (const float*)d_in[1];
  const float* beta = (const float*)d_in[2];
  const float* w_qkv = (const float*)d_in[3];
  const float* b_qkv = (const float*)d_in[4];
  const float* w_proj = (const float*)d_in[5];
  const float* b_proj = (const float*)d_in[6];
  float* out = (float*)d_out;

  char* ws = (char*)d_ws;
  short* xn_t = (short*)(ws);                  // 8 MB   (B,N,C) bf16
  short* wqkv_b = (short*)(ws + 8388608);      // 1.5 MB
  short* wproj_b = (short*)(ws + 9961472);     // 0.5 MB
  short* qbuf = (short*)(ws + 10485760);       // 8 MB   (BH,N,d)
  short* kbuf = (short*)(ws + 18874368);       // 8 MB   (BH,N,d)
  short* vtbuf = (short*)(ws + 27262976);      // 8 MB   (BH,d,N)
  short* aobuf = (short*)(ws + 35651584);      // 8 MB   (B,N,C)

  gn_kernel<<<dim3(256), dim3(256), 0, stream>>>(x, gamma, beta, xn_t);
  f2bf_kernel<<<dim3(768), dim3(256), 0, stream>>>(w_qkv, wqkv_b, 196608);
  f2bf_kernel<<<dim3(256), dim3(256), 0, stream>>>(w_proj, wproj_b, 65536);
  qkv_gemm<<<dim3(768), dim3(256), 0, stream>>>(wqkv_b, xn_t, b_qkv, qbuf, kbuf,
                                                vtbuf);
  attn_kernel<<<dim3(64, 8), dim3(512), 0, stream>>>(qbuf, kbuf, vtbuf, aobuf);
  proj_gemm<<<dim3(512), dim3(256), 0, stream>>>(wproj_b, aobuf, b_proj, x, out);
}

// Round 12
// 76.649 us; speedup vs baseline: 1.0866x; 1.0866x over previous
//
#include <hip/hip_runtime.h>

#define LOG2E 1.4426950408889634f

typedef short bf16x8 __attribute__((ext_vector_type(8)));
typedef short short4v __attribute__((ext_vector_type(4)));
typedef float f32x4 __attribute__((ext_vector_type(4)));
typedef _Float16 half4v __attribute__((ext_vector_type(4)));
typedef unsigned u32x4 __attribute__((ext_vector_type(4)));
typedef unsigned __attribute__((address_space(1))) u32g;
typedef unsigned __attribute__((address_space(3))) u32l;

#define MFMA16(a, b, c) __builtin_amdgcn_mfma_f32_16x16x32_bf16((a), (b), (c), 0, 0, 0)

__device__ __forceinline__ short f2bf(float f) {
  unsigned u = __builtin_bit_cast(unsigned, f);
  u += 0x7FFFu + ((u >> 16) & 1u);
  return (short)(u >> 16);
}

__device__ __forceinline__ unsigned cvtpk(float lo, float hi) {
  unsigned r;
  asm("v_cvt_pk_bf16_f32 %0, %1, %2" : "=v"(r) : "v"(lo), "v"(hi));
  return r;
}

__device__ __forceinline__ void g2l16(void* lds, const void* g) {
  __builtin_amdgcn_global_load_lds((u32g*)const_cast<void*>(g), (u32l*)lds, 16, 0, 0);
}

// ---------------------------------------------------------------------------
// GroupNorm: x (B,512,1024) f32 -> xn_t (B,1024,512) bf16   [transposed for GEMM]
// ---------------------------------------------------------------------------
__global__ __launch_bounds__(256) void gn_kernel(const float* __restrict__ x,
                                                 const float* __restrict__ gamma,
                                                 const float* __restrict__ beta,
                                                 short* __restrict__ xn_t) {
  __shared__ _Float16 xs[16 * 1024];  // 32 KB, row = channel, swizzled
  __shared__ float red[8];
  const int bg = blockIdx.x;
  const int b = bg >> 5, g = bg & 31;
  const int t = threadIdx.x;
  const float4* gx4 = (const float4*)(x + (size_t)(b * 512 + g * 16) * 1024);
  float s1 = 0.f, s2 = 0.f;
  for (int i = 0; i < 16; ++i) {
    float4 v = gx4[t + 256 * i];
    s1 += (v.x + v.y) + (v.z + v.w);
    s2 += (v.x * v.x + v.y * v.y) + (v.z * v.z + v.w * v.w);
    half4v pk = {(_Float16)v.x, (_Float16)v.y, (_Float16)v.z, (_Float16)v.w};
    *(half4v*)((char*)xs + i * 2048 + ((8 * t) ^ ((i & 7) << 4))) = pk;
  }
  for (int m = 1; m < 64; m <<= 1) {
    s1 += __shfl_xor(s1, m);
    s2 += __shfl_xor(s2, m);
  }
  if ((t & 63) == 0) {
    red[(t >> 6) * 2] = s1;
    red[(t >> 6) * 2 + 1] = s2;
  }
  __syncthreads();
  s1 = (red[0] + red[2]) + (red[4] + red[6]);
  s2 = (red[1] + red[3]) + (red[5] + red[7]);
  const float mean = s1 * (1.f / 16384.f);
  const float var = s2 * (1.f / 16384.f) - mean * mean;
  const float rstd = rsqrtf(var + 1e-6f);
  const int ci = t & 15;
  const float ga = gamma[g * 16 + ci] * rstd;
  const float be = beta[g * 16 + ci] - mean * ga;
  short* dst = xn_t + (size_t)b * 1024 * 512 + g * 16 + ci;
  const int sw = (ci & 7) << 4;
  for (int i = 0; i < 64; ++i) {
    int n = (t >> 4) + 16 * i;
    float v = (float)*(const _Float16*)((const char*)xs + ci * 2048 + ((2 * n) ^ sw));
    dst[(size_t)n * 512] = f2bf(fmaf(v, ga, be));
  }
}

// ---------------------------------------------------------------------------
// Merged f32->bf16 weight conversion: blocks [0,n1/… ) -> w_qkv, rest -> w_proj
// ---------------------------------------------------------------------------
__global__ __launch_bounds__(256) void f2bf2_kernel(const float* __restrict__ s1,
                                                    short* __restrict__ d1, int n1,
                                                    const float* __restrict__ s2,
                                                    short* __restrict__ d2) {
  int i = blockIdx.x * 256 + threadIdx.x;
  const float* s = (i < n1) ? s1 : s2;
  short* d = (i < n1) ? d1 : d2;
  int j = (i < n1) ? i : i - n1;
  float4 v = ((const float4*)s)[j];
  short4v o = {f2bf(v.x), f2bf(v.y), f2bf(v.z), f2bf(v.w)};
  *(short4v*)(d + (size_t)j * 4) = o;
}

// ---------------------------------------------------------------------------
// QKV GEMM, 2-phase prefetch + chunk-XOR LDS swizzle (R10 config — the R11
// XCD reindex regressed and is reverted).
// ---------------------------------------------------------------------------
__global__ __launch_bounds__(256) void qkv_gemm(const short* __restrict__ W,
                                                const short* __restrict__ xn,
                                                const float* __restrict__ bias,
                                                short* __restrict__ qbuf,
                                                short* __restrict__ kbuf,
                                                short* __restrict__ vtbuf) {
  __shared__ short a_sm[2][128 * 32];
  __shared__ short b_sm[2][128 * 32];
  const int t = threadIdx.x;
  const int lane = t & 63, w = t >> 6;
  const int nbase = blockIdx.x * 128;
  const int mbase = blockIdx.y * 128;
  const int b = blockIdx.z;
  const short* Asrc = W + (size_t)mbase * 512;
  const short* Bsrc = xn + (size_t)b * 1024 * 512 + (size_t)nbase * 512;

  const int j0 = t, j1 = t + 256;
  const int r0 = j0 >> 2, c0 = ((j0 & 3) ^ ((j0 >> 3) & 3)) * 8;
  const int r1 = j1 >> 2, c1 = ((j1 & 3) ^ ((j1 >> 3) & 3)) * 8;

#define STAGE(bi, kt)                                                 \
  {                                                                   \
    const int k0s = (kt) * 32;                                        \
    g2l16(&a_sm[bi][j0 * 8], Asrc + (size_t)r0 * 512 + k0s + c0);     \
    g2l16(&a_sm[bi][j1 * 8], Asrc + (size_t)r1 * 512 + k0s + c1);     \
    g2l16(&b_sm[bi][j0 * 8], Bsrc + (size_t)r0 * 512 + k0s + c0);     \
    g2l16(&b_sm[bi][j1 * 8], Bsrc + (size_t)r1 * 512 + k0s + c1);     \
  }

  const int wm = (w >> 1) * 64, wn = (w & 1) * 64;
  const int col = lane & 15, rg = lane >> 4;

  f32x4 acc[4][4] = {};

  STAGE(0, 0)
  __syncthreads();
  int cur = 0;

  for (int kt = 0; kt < 16; ++kt) {
    if (kt < 15) STAGE(cur ^ 1, kt + 1);
    bf16x8 af[4], bfr[4];
#pragma unroll
    for (int mf = 0; mf < 4; ++mf) {
      const int row = wm + mf * 16 + col;
      af[mf] = *(const bf16x8*)&a_sm[cur][row * 32 + ((rg ^ ((row >> 1) & 3)) * 8)];
    }
#pragma unroll
    for (int nf = 0; nf < 4; ++nf) {
      const int row = wn + nf * 16 + col;
      bfr[nf] = *(const bf16x8*)&b_sm[cur][row * 32 + ((rg ^ ((row >> 1) & 3)) * 8)];
    }
    __builtin_amdgcn_s_setprio(1);
#pragma unroll
    for (int mf = 0; mf < 4; ++mf)
#pragma unroll
      for (int nf = 0; nf < 4; ++nf)
        acc[mf][nf] = MFMA16(af[mf], bfr[nf], acc[mf][nf]);
    __builtin_amdgcn_s_setprio(0);
    __syncthreads();
    cur ^= 1;
  }
#undef STAGE

  const int section = mbase >> 9;
  for (int mf = 0; mf < 4; ++mf) {
    const int o0 = mbase + wm + mf * 16 + rg * 4;
    const int h = (o0 >> 6) & 7, d0 = o0 & 63;
    float b4[4];
    for (int r = 0; r < 4; ++r) b4[r] = bias[o0 + r];
    for (int nf = 0; nf < 4; ++nf) {
      const int n = nbase + wn + nf * 16 + col;
      if (section < 2) {
        short4v pkv;
        for (int r = 0; r < 4; ++r) pkv[r] = f2bf(acc[mf][nf][r] + b4[r]);
        short* dst = (section == 0) ? qbuf : kbuf;
        *(short4v*)&dst[((size_t)(b * 8 + h) * 1024 + n) * 64 + d0] = pkv;
      } else {
        for (int r = 0; r < 4; ++r)
          vtbuf[((size_t)(b * 8 + h) * 64 + d0 + r) * 1024 + n] =
              f2bf(acc[mf][nf][r] + b4[r]);
      }
    }
  }
}

// ---------------------------------------------------------------------------
// Flash attention, swapped-operand, 32 q-rows/wave, intra-block kv-split.
// NEW vs R10: LANE-LOCAL online softmax — no cross-lane ops on the common
// path. Row max: lane-local max + cheap __all test; the 2 shuffles + rescale
// run only when the running max grows >8 (rare after kt 0). Row sum: lrun
// accumulates lane-locally (rg slice); reduced across rg ONCE in epilogue.
// Removes 4 chain-serial ds_bpermute ops per mf*kt from the critical path.
// ---------------------------------------------------------------------------
__global__ __launch_bounds__(512, 4) void attn_kernel(const short* __restrict__ qbuf,
                                                      const short* __restrict__ kbuf,
                                                      const short* __restrict__ vtbuf,
                                                      short* __restrict__ ao) {
  __shared__ char smem[65536];
  const int t = threadIdx.x, lane = t & 63, w = t >> 6;
  const int col = lane & 15, rg = lane >> 4;
  const int grp = w >> 2, wq = w & 3;
  const int tg = t & 255;  // thread id within group (group = 4 waves)
  const int bh = blockIdx.x, qt = blockIdx.y;
  const int b = bh >> 3, h = bh & 7;
  const int qbase = qt * 128 + wq * 32;

  short* kb_ = (short*)(smem + grp * 32768);          // [2][64*64] K bufs
  short* vb_ = (short*)(smem + grp * 32768 + 16384);  // [2][64*64] V bufs

  // Q fragments (B-operand): aq[mf][kc], lane col = q, k = kc*32 + rg*8 + e
  bf16x8 aq[2][2];
  {
    const short* qp = qbuf + ((size_t)bh * 1024 + qbase) * 64;
#pragma unroll
    for (int mf = 0; mf < 2; ++mf)
#pragma unroll
      for (int kc = 0; kc < 2; ++kc)
        aq[mf][kc] = *(const bf16x8*)&qp[(mf * 16 + col) * 64 + kc * 32 + rg * 8];
  }

  // group kv-offsets: K rows += grp*512 ; V^T cols += grp*512
  const short* kp0 = kbuf + (size_t)bh * 65536 + grp * 32768;
  const short* vp0 = vtbuf + (size_t)bh * 65536 + grp * 512;

  uint4 kr[2], vr[2];
#define LOADK(kt)                                                                  \
  _Pragma("unroll") for (int i = 0; i < 2; ++i) {                                  \
    int j = tg + 256 * i;                                                          \
    kr[i] = *(const uint4*)&kp0[((size_t)(kt)*64 + (j >> 3)) * 64 + (j & 7) * 8];  \
  }
#define LOADV(kt)                                                                  \
  _Pragma("unroll") for (int i = 0; i < 2; ++i) {                                  \
    int j = tg + 256 * i;                                                          \
    vr[i] = *(const uint4*)&vp0[(size_t)(j >> 3) * 1024 + (kt)*64 + (j & 7) * 8];  \
  }
#define WRITEK(bi)                                                                 \
  _Pragma("unroll") for (int i = 0; i < 2; ++i) {                                  \
    int j = tg + 256 * i;                                                          \
    int row = j >> 3, off = j & 7;                                                 \
    *(uint4*)((char*)kb_ + (bi)*8192 + row * 128 + ((off * 16) ^ ((row & 7) << 4))) = kr[i]; \
  }
#define WRITEV(bi)                                                                 \
  _Pragma("unroll") for (int i = 0; i < 2; ++i) {                                  \
    int j = tg + 256 * i;                                                          \
    int d = j >> 3, g = j & 7;                                                     \
    int base = (g >> 2) * 64 + (g & 1) * 32 + ((g >> 1) & 1) * 8;                  \
    char* vb = (char*)vb_ + (bi)*8192 + d * 128;                                   \
    uint2 lo = {vr[i].x, vr[i].y}, hi = {vr[i].z, vr[i].w};                        \
    *(uint2*)(vb + ((base) ^ ((d & 7) << 4))) = lo;                                \
    *(uint2*)(vb + ((base + 16) ^ ((d & 7) << 4))) = hi;                           \
  }

  f32x4 oacc[2][4] = {};
  float mrun[2] = {-3e38f, -3e38f}, lrun[2] = {0.f, 0.f};
  const float kSL2E = 0.125f * LOG2E;  // attn scale folded into log2 domain
  int cur = 0;

  LOADK(0) LOADV(0) WRITEK(0) WRITEV(0)
  __syncthreads();

  for (int kt = 0; kt < 8; ++kt) {
    if (kt < 7) { LOADK(kt + 1) LOADV(kt + 1) }

    // S^T = K * Q^T : K fragment read once, shared by both mf
    f32x4 sT[2][4];
    __builtin_amdgcn_s_setprio(1);
#pragma unroll
    for (int nf = 0; nf < 4; ++nf) {
      const int n = nf * 16 + col;
      const char* kb = (const char*)kb_ + cur * 8192 + n * 128;
      const int sw = (n & 7) << 4;
      bf16x8 bk0 = *(const bf16x8*)(kb + ((rg * 16) ^ sw));
      bf16x8 bk1 = *(const bf16x8*)(kb + ((64 + rg * 16) ^ sw));
#pragma unroll
      for (int mf = 0; mf < 2; ++mf) {
        f32x4 z = {};
        z = MFMA16(bk0, aq[mf][0], z);
        sT[mf][nf] = MFMA16(bk1, aq[mf][1], z);
      }
    }
    __builtin_amdgcn_s_setprio(0);

    unsigned pk[2][4][2];
#pragma unroll
    for (int mf = 0; mf < 2; ++mf) {
      // lane-local (rg-slice) max; cross-lane work only on rescale-miss
      f32x4 mv = sT[mf][0];
#pragma unroll
      for (int nf = 1; nf < 4; ++nf)
#pragma unroll
        for (int r = 0; r < 4; ++r) mv[r] = fmaxf(mv[r], sT[mf][nf][r]);
      float mx = fmaxf(fmaxf(mv[0], mv[1]), fmaxf(mv[2], mv[3]));
      if (!__all(mx * 0.125f <= mrun[mf] + 8.f)) {  // rare after kt 0
        float mxr = fmaxf(mx, __shfl_xor(mx, 16));
        mxr = fmaxf(mxr, __shfl_xor(mxr, 32));
        const float pmax = mxr * 0.125f;             // row-wide max
        const float mnew = fmaxf(mrun[mf], pmax);
        const float alpha = __builtin_amdgcn_exp2f((mrun[mf] - mnew) * LOG2E);
        mrun[mf] = mnew;
        lrun[mf] *= alpha;
#pragma unroll
        for (int df = 0; df < 4; ++df) oacc[mf][df] *= alpha;
      }
      const float nege = mrun[mf] * LOG2E;
      float psum = 0.f;
#pragma unroll
      for (int nf = 0; nf < 4; ++nf) {
        float p0 = __builtin_amdgcn_exp2f(fmaf(sT[mf][nf][0], kSL2E, -nege));
        float p1 = __builtin_amdgcn_exp2f(fmaf(sT[mf][nf][1], kSL2E, -nege));
        float p2 = __builtin_amdgcn_exp2f(fmaf(sT[mf][nf][2], kSL2E, -nege));
        float p3 = __builtin_amdgcn_exp2f(fmaf(sT[mf][nf][3], kSL2E, -nege));
        psum += (p0 + p1) + (p2 + p3);
        pk[mf][nf][0] = cvtpk(p0, p1);
        pk[mf][nf][1] = cvtpk(p2, p3);
      }
      lrun[mf] += psum;  // lane-local partial sum (rg slice); reduced at end
    }

    // O^T += V^T * P^T : shared V b128 read feeds both Q-fragments' MFMAs
    __builtin_amdgcn_s_setprio(1);
#pragma unroll
    for (int kc = 0; kc < 2; ++kc) {
      bf16x8 pb[2];
#pragma unroll
      for (int mf = 0; mf < 2; ++mf) {
        u32x4 pbu = {pk[mf][2 * kc][0], pk[mf][2 * kc][1], pk[mf][2 * kc + 1][0],
                     pk[mf][2 * kc + 1][1]};
        pb[mf] = __builtin_bit_cast(bf16x8, pbu);
      }
#pragma unroll
      for (int df = 0; df < 4; ++df) {
        const int d = df * 16 + col;
        bf16x8 av = *(const bf16x8*)((const char*)vb_ + cur * 8192 + d * 128 +
                                     ((kc * 64 + rg * 16) ^ ((d & 7) << 4)));
#pragma unroll
        for (int mf = 0; mf < 2; ++mf) oacc[mf][df] = MFMA16(av, pb[mf], oacc[mf][df]);
      }
    }
    __builtin_amdgcn_s_setprio(0);

    if (kt < 7) { WRITEK(cur ^ 1) WRITEV(cur ^ 1) }
    __syncthreads();
    cur ^= 1;
  }

  // deferred row-sum reduce (once, instead of per-kt)
#pragma unroll
  for (int mf = 0; mf < 2; ++mf) {
    float l = lrun[mf];
    l += __shfl_xor(l, 16);
    l += __shfl_xor(l, 32);
    lrun[mf] = l;
  }

  // ---- in-block kv-split combine (LDS overlay on K/V buffers) ----
  f32x4* o_lds = (f32x4*)smem;                 // 32 KB: [w4][mf][df][lane]
  float* ml_lds = (float*)(smem + 32768);      // 4 KB: [w4][mf][lane][2]
  if (grp == 1) {
#pragma unroll
    for (int mf = 0; mf < 2; ++mf) {
#pragma unroll
      for (int df = 0; df < 4; ++df)
        o_lds[(((wq * 2 + mf) * 4) + df) * 64 + lane] = oacc[mf][df];
      ml_lds[((wq * 2 + mf) * 64 + lane) * 2] = mrun[mf];
      ml_lds[((wq * 2 + mf) * 64 + lane) * 2 + 1] = lrun[mf];
    }
  }
  __syncthreads();
  if (grp == 0) {
#pragma unroll
    for (int mf = 0; mf < 2; ++mf) {
      const float m1 = ml_lds[((wq * 2 + mf) * 64 + lane) * 2];
      const float l1 = ml_lds[((wq * 2 + mf) * 64 + lane) * 2 + 1];
      const float m = fmaxf(mrun[mf], m1);
      const float a0 = __builtin_amdgcn_exp2f((mrun[mf] - m) * LOG2E);
      const float a1 = __builtin_amdgcn_exp2f((m1 - m) * LOG2E);
      const float rl = 1.f / (lrun[mf] * a0 + l1 * a1);
      const int q = qbase + mf * 16 + col;
      short* dst = ao + ((size_t)b * 1024 + q) * 512 + h * 64;
#pragma unroll
      for (int df = 0; df < 4; ++df) {
        f32x4 o1 = o_lds[(((wq * 2 + mf) * 4) + df) * 64 + lane];
        short4v pkv;
#pragma unroll
        for (int r = 0; r < 4; ++r)
          pkv[r] = f2bf((oacc[mf][df][r] * a0 + o1[r] * a1) * rl);
        *(short4v*)&dst[df * 16 + rg * 4] = pkv;
      }
    }
  }
#undef LOADK
#undef LOADV
#undef WRITEK
#undef WRITEV
}

// ---------------------------------------------------------------------------
// Proj GEMM + bias + fp32 residual, 2-phase prefetch + swizzle, BM=64 tile
// (R10 config — XCD reindex reverted).
// ---------------------------------------------------------------------------
__global__ __launch_bounds__(256) void proj_gemm(const short* __restrict__ W,
                                                 const short* __restrict__ ao,
                                                 const float* __restrict__ bias,
                                                 const float* __restrict__ x,
                                                 float* __restrict__ out) {
  __shared__ short a_sm[2][64 * 32];
  __shared__ short b_sm[2][128 * 32];
  const int t = threadIdx.x;
  const int lane = t & 63, w = t >> 6;
  const int nbase = blockIdx.x * 128;
  const int mbase = blockIdx.y * 64;
  const int b = blockIdx.z;
  const short* Asrc = W + (size_t)mbase * 512;
  const short* Bsrc = ao + (size_t)b * 1024 * 512 + (size_t)nbase * 512;

  const int j0 = t, j1 = t + 256;
  const int r0 = j0 >> 2, c0 = ((j0 & 3) ^ ((j0 >> 3) & 3)) * 8;
  const int r1 = j1 >> 2, c1 = ((j1 & 3) ^ ((j1 >> 3) & 3)) * 8;

#define STAGE(bi, kt)                                                 \
  {                                                                   \
    const int k0s = (kt) * 32;                                        \
    g2l16(&a_sm[bi][j0 * 8], Asrc + (size_t)r0 * 512 + k0s + c0);     \
    g2l16(&b_sm[bi][j0 * 8], Bsrc + (size_t)r0 * 512 + k0s + c0);     \
    g2l16(&b_sm[bi][j1 * 8], Bsrc + (size_t)r1 * 512 + k0s + c1);     \
  }

  const int wm = (w >> 1) * 32, wn = (w & 1) * 64;
  const int col = lane & 15, rg = lane >> 4;

  f32x4 acc[2][4] = {};

  STAGE(0, 0)
  __syncthreads();
  int cur = 0;

  for (int kt = 0; kt < 16; ++kt) {
    if (kt < 15) STAGE(cur ^ 1, kt + 1);
    bf16x8 af[2], bfr[4];
#pragma unroll
    for (int mf = 0; mf < 2; ++mf) {
      const int row = wm + mf * 16 + col;
      af[mf] = *(const bf16x8*)&a_sm[cur][row * 32 + ((rg ^ ((row >> 1) & 3)) * 8)];
    }
#pragma unroll
    for (int nf = 0; nf < 4; ++nf) {
      const int row = wn + nf * 16 + col;
      bfr[nf] = *(const bf16x8*)&b_sm[cur][row * 32 + ((rg ^ ((row >> 1) & 3)) * 8)];
    }
    __builtin_amdgcn_s_setprio(1);
#pragma unroll
    for (int mf = 0; mf < 2; ++mf)
#pragma unroll
      for (int nf = 0; nf < 4; ++nf)
        acc[mf][nf] = MFMA16(af[mf], bfr[nf], acc[mf][nf]);
    __builtin_amdgcn_s_setprio(0);
    __syncthreads();
    cur ^= 1;
  }
#undef STAGE

  for (int mf = 0; mf < 2; ++mf) {
    const int o0 = mbase + wm + mf * 16 + rg * 4;
    float b4[4];
    for (int r = 0; r < 4; ++r) b4[r] = bias[o0 + r];
    for (int nf = 0; nf < 4; ++nf) {
      const int n = nbase + wn + nf * 16 + col;
      for (int r = 0; r < 4; ++r) {
        size_t idx = ((size_t)b * 512 + o0 + r) * 1024 + n;
        out[idx] = x[idx] + acc[mf][nf][r] + b4[r];
      }
    }
  }
}

// ---------------------------------------------------------------------------
extern "C" void kernel_launch(void* const* d_in, const int* in_sizes, int n_in,
                              void* d_out, int out_size, void* d_ws, size_t ws_size,
                              hipStream_t stream) {
  const float* x = (const float*)d_in[0];
  const float* gamma = (const float*)d_in[1];
  const float* beta = (const float*)d_in[2];
  const float* w_qkv = (const float*)d_in[3];
  const float* b_qkv = (const float*)d_in[4];
  const float* w_proj = (const float*)d_in[5];
  const float* b_proj = (const float*)d_in[6];
  float* out = (float*)d_out;

  char* ws = (char*)d_ws;
  short* xn_t = (short*)(ws);                  // 8 MB   (B,N,C) bf16
  short* wqkv_b = (short*)(ws + 8388608);      // 1.5 MB
  short* wproj_b = (short*)(ws + 9961472);     // 0.5 MB
  short* qbuf = (short*)(ws + 10485760);       // 8 MB   (BH,N,d)
  short* kbuf = (short*)(ws + 18874368);       // 8 MB   (BH,N,d)
  short* vtbuf = (short*)(ws + 27262976);      // 8 MB   (BH,d,N)
  short* aobuf = (short*)(ws + 35651584);      // 8 MB   (B,N,C)

  gn_kernel<<<dim3(256), dim3(256), 0, stream>>>(x, gamma, beta, xn_t);
  f2bf2_kernel<<<dim3(1024), dim3(256), 0, stream>>>(w_qkv, wqkv_b, 196608, w_proj,
                                                     wproj_b);
  qkv_gemm<<<dim3(8, 12, 8), dim3(256), 0, stream>>>(wqkv_b, xn_t, b_qkv, qbuf, kbuf,
                                                     vtbuf);
  attn_kernel<<<dim3(64, 8), dim3(512), 0, stream>>>(qbuf, kbuf, vtbuf, aobuf);
  proj_gemm<<<dim3(8, 8, 8), dim3(256), 0, stream>>>(wproj_b, aobuf, b_proj, x, out);
}

// Round 13
// 75.574 us; speedup vs baseline: 1.1020x; 1.0142x over previous
//
#include <hip/hip_runtime.h>

#define LOG2E 1.4426950408889634f

typedef short bf16x8 __attribute__((ext_vector_type(8)));
typedef short short4v __attribute__((ext_vector_type(4)));
typedef float f32x4 __attribute__((ext_vector_type(4)));
typedef _Float16 half4v __attribute__((ext_vector_type(4)));
typedef unsigned u32x4 __attribute__((ext_vector_type(4)));
typedef unsigned __attribute__((address_space(1))) u32g;
typedef unsigned __attribute__((address_space(3))) u32l;

#define MFMA16(a, b, c) __builtin_amdgcn_mfma_f32_16x16x32_bf16((a), (b), (c), 0, 0, 0)

__device__ __forceinline__ short f2bf(float f) {
  unsigned u = __builtin_bit_cast(unsigned, f);
  u += 0x7FFFu + ((u >> 16) & 1u);
  return (short)(u >> 16);
}

__device__ __forceinline__ unsigned cvtpk(float lo, float hi) {
  unsigned r;
  asm("v_cvt_pk_bf16_f32 %0, %1, %2" : "=v"(r) : "v"(lo), "v"(hi));
  return r;
}

__device__ __forceinline__ void g2l16(void* lds, const void* g) {
  __builtin_amdgcn_global_load_lds((u32g*)const_cast<void*>(g), (u32l*)lds, 16, 0, 0);
}

// ---------------------------------------------------------------------------
// GroupNorm: x (B,512,1024) f32 -> xn_t (B,1024,512) bf16   [transposed for GEMM]
// ---------------------------------------------------------------------------
__global__ __launch_bounds__(256) void gn_kernel(const float* __restrict__ x,
                                                 const float* __restrict__ gamma,
                                                 const float* __restrict__ beta,
                                                 short* __restrict__ xn_t) {
  __shared__ _Float16 xs[16 * 1024];  // 32 KB, row = channel, swizzled
  __shared__ float red[8];
  const int bg = blockIdx.x;
  const int b = bg >> 5, g = bg & 31;
  const int t = threadIdx.x;
  const float4* gx4 = (const float4*)(x + (size_t)(b * 512 + g * 16) * 1024);
  float s1 = 0.f, s2 = 0.f;
  for (int i = 0; i < 16; ++i) {
    float4 v = gx4[t + 256 * i];
    s1 += (v.x + v.y) + (v.z + v.w);
    s2 += (v.x * v.x + v.y * v.y) + (v.z * v.z + v.w * v.w);
    half4v pk = {(_Float16)v.x, (_Float16)v.y, (_Float16)v.z, (_Float16)v.w};
    *(half4v*)((char*)xs + i * 2048 + ((8 * t) ^ ((i & 7) << 4))) = pk;
  }
  for (int m = 1; m < 64; m <<= 1) {
    s1 += __shfl_xor(s1, m);
    s2 += __shfl_xor(s2, m);
  }
  if ((t & 63) == 0) {
    red[(t >> 6) * 2] = s1;
    red[(t >> 6) * 2 + 1] = s2;
  }
  __syncthreads();
  s1 = (red[0] + red[2]) + (red[4] + red[6]);
  s2 = (red[1] + red[3]) + (red[5] + red[7]);
  const float mean = s1 * (1.f / 16384.f);
  const float var = s2 * (1.f / 16384.f) - mean * mean;
  const float rstd = rsqrtf(var + 1e-6f);
  const int ci = t & 15;
  const float ga = gamma[g * 16 + ci] * rstd;
  const float be = beta[g * 16 + ci] - mean * ga;
  short* dst = xn_t + (size_t)b * 1024 * 512 + g * 16 + ci;
  const int sw = (ci & 7) << 4;
  for (int i = 0; i < 64; ++i) {
    int n = (t >> 4) + 16 * i;
    float v = (float)*(const _Float16*)((const char*)xs + ci * 2048 + ((2 * n) ^ sw));
    dst[(size_t)n * 512] = f2bf(fmaf(v, ga, be));
  }
}

// ---------------------------------------------------------------------------
// Merged f32->bf16 weight conversion
// ---------------------------------------------------------------------------
__global__ __launch_bounds__(256) void f2bf2_kernel(const float* __restrict__ s1,
                                                    short* __restrict__ d1, int n1,
                                                    const float* __restrict__ s2,
                                                    short* __restrict__ d2) {
  int i = blockIdx.x * 256 + threadIdx.x;
  const float* s = (i < n1) ? s1 : s2;
  short* d = (i < n1) ? d1 : d2;
  int j = (i < n1) ? i : i - n1;
  float4 v = ((const float4*)s)[j];
  short4v o = {f2bf(v.x), f2bf(v.y), f2bf(v.z), f2bf(v.w)};
  *(short4v*)(d + (size_t)j * 4) = o;
}

// ---------------------------------------------------------------------------
// QKV GEMM — T4 counted-vmcnt pipeline: TRIPLE-buffered LDS, stage(kt+1) ->
// slot (kt+1)%3, then `s_waitcnt vmcnt(4)` (forces only the PREVIOUS stage's
// loads; the 4 new ones stay in flight across the barrier) + raw s_barrier.
// One barrier/kt; triple buffering makes it race-free (slot re-written at kt
// was last read at kt-2, separated by barrier(kt-1)). Replaces the
// __syncthreads whose implicit vmcnt(0) drained the prefetch every kt.
// ---------------------------------------------------------------------------
__global__ __launch_bounds__(256) void qkv_gemm(const short* __restrict__ W,
                                                const short* __restrict__ xn,
                                                const float* __restrict__ bias,
                                                short* __restrict__ qbuf,
                                                short* __restrict__ kbuf,
                                                short* __restrict__ vtbuf) {
  __shared__ short a_sm[3][128 * 32];
  __shared__ short b_sm[3][128 * 32];
  const int t = threadIdx.x;
  const int lane = t & 63, w = t >> 6;
  const int nbase = blockIdx.x * 128;
  const int mbase = blockIdx.y * 128;
  const int b = blockIdx.z;
  const short* Asrc = W + (size_t)mbase * 512;
  const short* Bsrc = xn + (size_t)b * 1024 * 512 + (size_t)nbase * 512;

  const int j0 = t, j1 = t + 256;
  const int r0 = j0 >> 2, c0 = ((j0 & 3) ^ ((j0 >> 3) & 3)) * 8;
  const int r1 = j1 >> 2, c1 = ((j1 & 3) ^ ((j1 >> 3) & 3)) * 8;

#define STAGE(bi, kt)                                                 \
  {                                                                   \
    const int k0s = (kt) * 32;                                        \
    g2l16(&a_sm[bi][j0 * 8], Asrc + (size_t)r0 * 512 + k0s + c0);     \
    g2l16(&a_sm[bi][j1 * 8], Asrc + (size_t)r1 * 512 + k0s + c1);     \
    g2l16(&b_sm[bi][j0 * 8], Bsrc + (size_t)r0 * 512 + k0s + c0);     \
    g2l16(&b_sm[bi][j1 * 8], Bsrc + (size_t)r1 * 512 + k0s + c1);     \
  }

  const int wm = (w >> 1) * 64, wn = (w & 1) * 64;
  const int col = lane & 15, rg = lane >> 4;

  f32x4 acc[4][4] = {};

  STAGE(0, 0)
  int cur = 0, nxt = 1;

  for (int kt = 0; kt < 16; ++kt) {
    if (kt < 15) {
      STAGE(nxt, kt + 1)
      asm volatile("s_waitcnt vmcnt(4)" ::: "memory");
    } else {
      asm volatile("s_waitcnt vmcnt(0)" ::: "memory");
    }
    __builtin_amdgcn_s_barrier();
    __builtin_amdgcn_sched_barrier(0);

    bf16x8 af[4], bfr[4];
#pragma unroll
    for (int mf = 0; mf < 4; ++mf) {
      const int row = wm + mf * 16 + col;
      af[mf] = *(const bf16x8*)&a_sm[cur][row * 32 + ((rg ^ ((row >> 1) & 3)) * 8)];
    }
#pragma unroll
    for (int nf = 0; nf < 4; ++nf) {
      const int row = wn + nf * 16 + col;
      bfr[nf] = *(const bf16x8*)&b_sm[cur][row * 32 + ((rg ^ ((row >> 1) & 3)) * 8)];
    }
    __builtin_amdgcn_s_setprio(1);
#pragma unroll
    for (int mf = 0; mf < 4; ++mf)
#pragma unroll
      for (int nf = 0; nf < 4; ++nf)
        acc[mf][nf] = MFMA16(af[mf], bfr[nf], acc[mf][nf]);
    __builtin_amdgcn_s_setprio(0);
    cur = nxt;
    nxt = (nxt == 2) ? 0 : nxt + 1;
  }
#undef STAGE

  const int section = mbase >> 9;
  for (int mf = 0; mf < 4; ++mf) {
    const int o0 = mbase + wm + mf * 16 + rg * 4;
    const int h = (o0 >> 6) & 7, d0 = o0 & 63;
    float b4[4];
    for (int r = 0; r < 4; ++r) b4[r] = bias[o0 + r];
    for (int nf = 0; nf < 4; ++nf) {
      const int n = nbase + wn + nf * 16 + col;
      if (section < 2) {
        short4v pkv;
        for (int r = 0; r < 4; ++r) pkv[r] = f2bf(acc[mf][nf][r] + b4[r]);
        short* dst = (section == 0) ? qbuf : kbuf;
        *(short4v*)&dst[((size_t)(b * 8 + h) * 1024 + n) * 64 + d0] = pkv;
      } else {
        for (int r = 0; r < 4; ++r)
          vtbuf[((size_t)(b * 8 + h) * 64 + d0 + r) * 1024 + n] =
              f2bf(acc[mf][nf][r] + b4[r]);
      }
    }
  }
}

// ---------------------------------------------------------------------------
// Flash attention (unchanged from R12 — lane-local online softmax, kv-split).
// ---------------------------------------------------------------------------
__global__ __launch_bounds__(512, 4) void attn_kernel(const short* __restrict__ qbuf,
                                                      const short* __restrict__ kbuf,
                                                      const short* __restrict__ vtbuf,
                                                      short* __restrict__ ao) {
  __shared__ char smem[65536];
  const int t = threadIdx.x, lane = t & 63, w = t >> 6;
  const int col = lane & 15, rg = lane >> 4;
  const int grp = w >> 2, wq = w & 3;
  const int tg = t & 255;
  const int bh = blockIdx.x, qt = blockIdx.y;
  const int b = bh >> 3, h = bh & 7;
  const int qbase = qt * 128 + wq * 32;

  short* kb_ = (short*)(smem + grp * 32768);
  short* vb_ = (short*)(smem + grp * 32768 + 16384);

  bf16x8 aq[2][2];
  {
    const short* qp = qbuf + ((size_t)bh * 1024 + qbase) * 64;
#pragma unroll
    for (int mf = 0; mf < 2; ++mf)
#pragma unroll
      for (int kc = 0; kc < 2; ++kc)
        aq[mf][kc] = *(const bf16x8*)&qp[(mf * 16 + col) * 64 + kc * 32 + rg * 8];
  }

  const short* kp0 = kbuf + (size_t)bh * 65536 + grp * 32768;
  const short* vp0 = vtbuf + (size_t)bh * 65536 + grp * 512;

  uint4 kr[2], vr[2];
#define LOADK(kt)                                                                  \
  _Pragma("unroll") for (int i = 0; i < 2; ++i) {                                  \
    int j = tg + 256 * i;                                                          \
    kr[i] = *(const uint4*)&kp0[((size_t)(kt)*64 + (j >> 3)) * 64 + (j & 7) * 8];  \
  }
#define LOADV(kt)                                                                  \
  _Pragma("unroll") for (int i = 0; i < 2; ++i) {                                  \
    int j = tg + 256 * i;                                                          \
    vr[i] = *(const uint4*)&vp0[(size_t)(j >> 3) * 1024 + (kt)*64 + (j & 7) * 8];  \
  }
#define WRITEK(bi)                                                                 \
  _Pragma("unroll") for (int i = 0; i < 2; ++i) {                                  \
    int j = tg + 256 * i;                                                          \
    int row = j >> 3, off = j & 7;                                                 \
    *(uint4*)((char*)kb_ + (bi)*8192 + row * 128 + ((off * 16) ^ ((row & 7) << 4))) = kr[i]; \
  }
#define WRITEV(bi)                                                                 \
  _Pragma("unroll") for (int i = 0; i < 2; ++i) {                                  \
    int j = tg + 256 * i;                                                          \
    int d = j >> 3, g = j & 7;                                                     \
    int base = (g >> 2) * 64 + (g & 1) * 32 + ((g >> 1) & 1) * 8;                  \
    char* vb = (char*)vb_ + (bi)*8192 + d * 128;                                   \
    uint2 lo = {vr[i].x, vr[i].y}, hi = {vr[i].z, vr[i].w};                        \
    *(uint2*)(vb + ((base) ^ ((d & 7) << 4))) = lo;                                \
    *(uint2*)(vb + ((base + 16) ^ ((d & 7) << 4))) = hi;                           \
  }

  f32x4 oacc[2][4] = {};
  float mrun[2] = {-3e38f, -3e38f}, lrun[2] = {0.f, 0.f};
  const float kSL2E = 0.125f * LOG2E;
  int cur = 0;

  LOADK(0) LOADV(0) WRITEK(0) WRITEV(0)
  __syncthreads();

  for (int kt = 0; kt < 8; ++kt) {
    if (kt < 7) { LOADK(kt + 1) LOADV(kt + 1) }

    f32x4 sT[2][4];
    __builtin_amdgcn_s_setprio(1);
#pragma unroll
    for (int nf = 0; nf < 4; ++nf) {
      const int n = nf * 16 + col;
      const char* kb = (const char*)kb_ + cur * 8192 + n * 128;
      const int sw = (n & 7) << 4;
      bf16x8 bk0 = *(const bf16x8*)(kb + ((rg * 16) ^ sw));
      bf16x8 bk1 = *(const bf16x8*)(kb + ((64 + rg * 16) ^ sw));
#pragma unroll
      for (int mf = 0; mf < 2; ++mf) {
        f32x4 z = {};
        z = MFMA16(bk0, aq[mf][0], z);
        sT[mf][nf] = MFMA16(bk1, aq[mf][1], z);
      }
    }
    __builtin_amdgcn_s_setprio(0);

    unsigned pk[2][4][2];
#pragma unroll
    for (int mf = 0; mf < 2; ++mf) {
      f32x4 mv = sT[mf][0];
#pragma unroll
      for (int nf = 1; nf < 4; ++nf)
#pragma unroll
        for (int r = 0; r < 4; ++r) mv[r] = fmaxf(mv[r], sT[mf][nf][r]);
      float mx = fmaxf(fmaxf(mv[0], mv[1]), fmaxf(mv[2], mv[3]));
      if (!__all(mx * 0.125f <= mrun[mf] + 8.f)) {
        float mxr = fmaxf(mx, __shfl_xor(mx, 16));
        mxr = fmaxf(mxr, __shfl_xor(mxr, 32));
        const float pmax = mxr * 0.125f;
        const float mnew = fmaxf(mrun[mf], pmax);
        const float alpha = __builtin_amdgcn_exp2f((mrun[mf] - mnew) * LOG2E);
        mrun[mf] = mnew;
        lrun[mf] *= alpha;
#pragma unroll
        for (int df = 0; df < 4; ++df) oacc[mf][df] *= alpha;
      }
      const float nege = mrun[mf] * LOG2E;
      float psum = 0.f;
#pragma unroll
      for (int nf = 0; nf < 4; ++nf) {
        float p0 = __builtin_amdgcn_exp2f(fmaf(sT[mf][nf][0], kSL2E, -nege));
        float p1 = __builtin_amdgcn_exp2f(fmaf(sT[mf][nf][1], kSL2E, -nege));
        float p2 = __builtin_amdgcn_exp2f(fmaf(sT[mf][nf][2], kSL2E, -nege));
        float p3 = __builtin_amdgcn_exp2f(fmaf(sT[mf][nf][3], kSL2E, -nege));
        psum += (p0 + p1) + (p2 + p3);
        pk[mf][nf][0] = cvtpk(p0, p1);
        pk[mf][nf][1] = cvtpk(p2, p3);
      }
      lrun[mf] += psum;
    }

    __builtin_amdgcn_s_setprio(1);
#pragma unroll
    for (int kc = 0; kc < 2; ++kc) {
      bf16x8 pb[2];
#pragma unroll
      for (int mf = 0; mf < 2; ++mf) {
        u32x4 pbu = {pk[mf][2 * kc][0], pk[mf][2 * kc][1], pk[mf][2 * kc + 1][0],
                     pk[mf][2 * kc + 1][1]};
        pb[mf] = __builtin_bit_cast(bf16x8, pbu);
      }
#pragma unroll
      for (int df = 0; df < 4; ++df) {
        const int d = df * 16 + col;
        bf16x8 av = *(const bf16x8*)((const char*)vb_ + cur * 8192 + d * 128 +
                                     ((kc * 64 + rg * 16) ^ ((d & 7) << 4)));
#pragma unroll
        for (int mf = 0; mf < 2; ++mf) oacc[mf][df] = MFMA16(av, pb[mf], oacc[mf][df]);
      }
    }
    __builtin_amdgcn_s_setprio(0);

    if (kt < 7) { WRITEK(cur ^ 1) WRITEV(cur ^ 1) }
    __syncthreads();
    cur ^= 1;
  }

#pragma unroll
  for (int mf = 0; mf < 2; ++mf) {
    float l = lrun[mf];
    l += __shfl_xor(l, 16);
    l += __shfl_xor(l, 32);
    lrun[mf] = l;
  }

  f32x4* o_lds = (f32x4*)smem;
  float* ml_lds = (float*)(smem + 32768);
  if (grp == 1) {
#pragma unroll
    for (int mf = 0; mf < 2; ++mf) {
#pragma unroll
      for (int df = 0; df < 4; ++df)
        o_lds[(((wq * 2 + mf) * 4) + df) * 64 + lane] = oacc[mf][df];
      ml_lds[((wq * 2 + mf) * 64 + lane) * 2] = mrun[mf];
      ml_lds[((wq * 2 + mf) * 64 + lane) * 2 + 1] = lrun[mf];
    }
  }
  __syncthreads();
  if (grp == 0) {
#pragma unroll
    for (int mf = 0; mf < 2; ++mf) {
      const float m1 = ml_lds[((wq * 2 + mf) * 64 + lane) * 2];
      const float l1 = ml_lds[((wq * 2 + mf) * 64 + lane) * 2 + 1];
      const float m = fmaxf(mrun[mf], m1);
      const float a0 = __builtin_amdgcn_exp2f((mrun[mf] - m) * LOG2E);
      const float a1 = __builtin_amdgcn_exp2f((m1 - m) * LOG2E);
      const float rl = 1.f / (lrun[mf] * a0 + l1 * a1);
      const int q = qbase + mf * 16 + col;
      short* dst = ao + ((size_t)b * 1024 + q) * 512 + h * 64;
#pragma unroll
      for (int df = 0; df < 4; ++df) {
        f32x4 o1 = o_lds[(((wq * 2 + mf) * 4) + df) * 64 + lane];
        short4v pkv;
#pragma unroll
        for (int r = 0; r < 4; ++r)
          pkv[r] = f2bf((oacc[mf][df][r] * a0 + o1[r] * a1) * rl);
        *(short4v*)&dst[df * 16 + rg * 4] = pkv;
      }
    }
  }
#undef LOADK
#undef LOADV
#undef WRITEK
#undef WRITEV
}

// ---------------------------------------------------------------------------
// Proj GEMM + bias + fp32 residual — same T4 counted-vmcnt triple-buffer
// pipeline as qkv (3 loads/stage here -> vmcnt(3)).
// ---------------------------------------------------------------------------
__global__ __launch_bounds__(256) void proj_gemm(const short* __restrict__ W,
                                                 const short* __restrict__ ao,
                                                 const float* __restrict__ bias,
                                                 const float* __restrict__ x,
                                                 float* __restrict__ out) {
  __shared__ short a_sm[3][64 * 32];
  __shared__ short b_sm[3][128 * 32];
  const int t = threadIdx.x;
  const int lane = t & 63, w = t >> 6;
  const int nbase = blockIdx.x * 128;
  const int mbase = blockIdx.y * 64;
  const int b = blockIdx.z;
  const short* Asrc = W + (size_t)mbase * 512;
  const short* Bsrc = ao + (size_t)b * 1024 * 512 + (size_t)nbase * 512;

  const int j0 = t, j1 = t + 256;
  const int r0 = j0 >> 2, c0 = ((j0 & 3) ^ ((j0 >> 3) & 3)) * 8;
  const int r1 = j1 >> 2, c1 = ((j1 & 3) ^ ((j1 >> 3) & 3)) * 8;

#define STAGE(bi, kt)                                                 \
  {                                                                   \
    const int k0s = (kt) * 32;                                        \
    g2l16(&a_sm[bi][j0 * 8], Asrc + (size_t)r0 * 512 + k0s + c0);     \
    g2l16(&b_sm[bi][j0 * 8], Bsrc + (size_t)r0 * 512 + k0s + c0);     \
    g2l16(&b_sm[bi][j1 * 8], Bsrc + (size_t)r1 * 512 + k0s + c1);     \
  }

  const int wm = (w >> 1) * 32, wn = (w & 1) * 64;
  const int col = lane & 15, rg = lane >> 4;

  f32x4 acc[2][4] = {};

  STAGE(0, 0)
  int cur = 0, nxt = 1;

  for (int kt = 0; kt < 16; ++kt) {
    if (kt < 15) {
      STAGE(nxt, kt + 1)
      asm volatile("s_waitcnt vmcnt(3)" ::: "memory");
    } else {
      asm volatile("s_waitcnt vmcnt(0)" ::: "memory");
    }
    __builtin_amdgcn_s_barrier();
    __builtin_amdgcn_sched_barrier(0);

    bf16x8 af[2], bfr[4];
#pragma unroll
    for (int mf = 0; mf < 2; ++mf) {
      const int row = wm + mf * 16 + col;
      af[mf] = *(const bf16x8*)&a_sm[cur][row * 32 + ((rg ^ ((row >> 1) & 3)) * 8)];
    }
#pragma unroll
    for (int nf = 0; nf < 4; ++nf) {
      const int row = wn + nf * 16 + col;
      bfr[nf] = *(const bf16x8*)&b_sm[cur][row * 32 + ((rg ^ ((row >> 1) & 3)) * 8)];
    }
    __builtin_amdgcn_s_setprio(1);
#pragma unroll
    for (int mf = 0; mf < 2; ++mf)
#pragma unroll
      for (int nf = 0; nf < 4; ++nf)
        acc[mf][nf] = MFMA16(af[mf], bfr[nf], acc[mf][nf]);
    __builtin_amdgcn_s_setprio(0);
    cur = nxt;
    nxt = (nxt == 2) ? 0 : nxt + 1;
  }
#undef STAGE

  for (int mf = 0; mf < 2; ++mf) {
    const int o0 = mbase + wm + mf * 16 + rg * 4;
    float b4[4];
    for (int r = 0; r < 4; ++r) b4[r] = bias[o0 + r];
    for (int nf = 0; nf < 4; ++nf) {
      const int n = nbase + wn + nf * 16 + col;
      for (int r = 0; r < 4; ++r) {
        size_t idx = ((size_t)b * 512 + o0 + r) * 1024 + n;
        out[idx] = x[idx] + acc[mf][nf][r] + b4[r];
      }
    }
  }
}

// ---------------------------------------------------------------------------
extern "C" void kernel_launch(void* const* d_in, const int* in_sizes, int n_in,
                              void* d_out, int out_size, void* d_ws, size_t ws_size,
                              hipStream_t stream) {
  const float* x = (const float*)d_in[0];
  const float* gamma = (const float*)d_in[1];
  const float* beta = (const float*)d_in[2];
  const float* w_qkv = (const float*)d_in[3];
  const float* b_qkv = (const float*)d_in[4];
  const float* w_proj = (const float*)d_in[5];
  const float* b_proj = (const float*)d_in[6];
  float* out = (float*)d_out;

  char* ws = (char*)d_ws;
  short* xn_t = (short*)(ws);                  // 8 MB   (B,N,C) bf16
  short* wqkv_b = (short*)(ws + 8388608);      // 1.5 MB
  short* wproj_b = (short*)(ws + 9961472);     // 0.5 MB
  short* qbuf = (short*)(ws + 10485760);       // 8 MB   (BH,N,d)
  short* kbuf = (short*)(ws + 18874368);       // 8 MB   (BH,N,d)
  short* vtbuf = (short*)(ws + 27262976);      // 8 MB   (BH,d,N)
  short* aobuf = (short*)(ws + 35651584);      // 8 MB   (B,N,C)

  gn_kernel<<<dim3(256), dim3(256), 0, stream>>>(x, gamma, beta, xn_t);
  f2bf2_kernel<<<dim3(1024), dim3(256), 0, stream>>>(w_qkv, wqkv_b, 196608, w_proj,
                                                     wproj_b);
  qkv_gemm<<<dim3(8, 12, 8), dim3(256), 0, stream>>>(wqkv_b, xn_t, b_qkv, qbuf, kbuf,
                                                     vtbuf);
  attn_kernel<<<dim3(64, 8), dim3(512), 0, stream>>>(qbuf, kbuf, vtbuf, aobuf);
  proj_gemm<<<dim3(8, 8, 8), dim3(256), 0, stream>>>(wproj_b, aobuf, b_proj, x, out);
}